// Round 7
// baseline (94.814 us; speedup 1.0000x reference)
//
#include <hip/hip_runtime.h>
#include <hip/hip_bf16.h>

// Contrastive loss, B=8192, D=128, 100 classes, margin=2.
// R7: LDS-staged fragments. R4-R6 were L2-latency-bound: 32 x 1KB fragment
// loads per wave straight from L2 (~200cyc) with only ~2-5 waves/SIMD.
// fbp's fragment-order layout makes each 128-row tile a CONTIGUOUS 32KB span
// (panel-major), so: stage A+B (64KB) into LDS coalesced (16B/lane), then
// ds_read_b128 fragments (lane*16B -> conflict-free). Halves L2 traffic
// (intra-block 2x reuse moves to LDS), VGPRs back down, 2 blocks/CU overlap
// hides the stage barrier (R3's structure -- its 133us was the atomic wall).
//   fbp[((p*4+ks)*64+lane)*8+j] = F_bf16[p*16+(lane&15)][ks*32+(lane>>4)*8+j]
// Known harness floor ~46us/iter (268MB d_ws 0xAA poison fill ~41us + restore).
// No global atomics (R4: same-address fp32 atomics serialize ~15ns each).
// pos_count>0 always: 8192 rows, 100 classes -> pigeonhole duplicate labels.

#define BN 8192
#define DD 128
#define NTILES 64                              // BN / 128
#define NBLOCKS (NTILES * (NTILES + 1) / 2)    // 2080
#define LS 136                                 // prep LDS row stride (shorts)

typedef __attribute__((ext_vector_type(8))) short bf16x8;   // 8 bf16 = 4 VGPRs
typedef __attribute__((ext_vector_type(4))) float f32x4;

// One block per 16-row panel. Coalesced read -> bf16 -> LDS transpose ->
// coalesced fragment-order write. Also emits (norm^2, label) meta.
__global__ __launch_bounds__(256) void prep_kernel(const float* __restrict__ f,
        const int* __restrict__ labels, short* __restrict__ fbp,
        float2* __restrict__ meta) {
    const int tid = threadIdx.x;
    const int p = blockIdx.x;                  // panel index (16 rows)
    __shared__ unsigned short ls[16][LS];

    const int r = tid >> 4;                    // row in panel (16 threads/row)
    const int c = (tid & 15) * 8;              // col of this thread's 8 floats
    const float* src = f + ((size_t)p * 16 + r) * DD + c;
    float4 a = *(const float4*)src;
    float4 b = *(const float4*)(src + 4);
    float rv[8] = {a.x, a.y, a.z, a.w, b.x, b.y, b.z, b.w};
    float s = 0.f;
#pragma unroll
    for (int j = 0; j < 8; j++) {
        __hip_bfloat16 h = __float2bfloat16(rv[j]);
        ls[r][c + j] = *(unsigned short*)&h;
        float rr = __bfloat162float(h);
        s = fmaf(rr, rr, s);
    }
    // row norm: reduce across the 16 consecutive lanes of this row
#pragma unroll
    for (int off = 8; off > 0; off >>= 1) s += __shfl_down(s, off, 16);
    if ((tid & 15) == 0) meta[p * 16 + r] = make_float2(s, (float)labels[p * 16 + r]);
    __syncthreads();

    // wave w = k-step ks; 16B/lane LDS read, 1KB contiguous global write
    const int w = tid >> 6, lane = tid & 63;
    const int l15 = lane & 15, quad = lane >> 4;
    bf16x8 pack = *(const bf16x8*)&ls[l15][w * 32 + quad * 8];
    *(bf16x8*)(fbp + ((size_t)(p * 4 + w) * 64 + lane) * 8) = pack;
}

__global__ __launch_bounds__(256) void pair_kernel(
        const short* __restrict__ fbp, const float2* __restrict__ meta,
        float2* __restrict__ partial) {
    // triangular decode: block t -> (bx <= by); i-tile = bx, j-tile = by
    const int t = blockIdx.x;
    int by = (int)((sqrtf(8.f * (float)t + 1.f) - 1.f) * 0.5f);
    while ((by + 1) * (by + 2) / 2 <= t) by++;
    while (by * (by + 1) / 2 > t) by--;
    const int bx = t - by * (by + 1) / 2;
    const bool diag = (bx == by);

    const int tid = threadIdx.x;
    const int wave = tid >> 6, lane = tid & 63;
    const int wx = wave & 1, wy = wave >> 1;     // j / i subtile
    const int i0 = bx * 128 + wy * 64;
    const int j0 = by * 128 + wx * 64;
    const int l15 = lane & 15, quad = lane >> 4;

    // ---- stage tiles: A = fbp[bx*32KB ..], B = fbp[by*32KB ..], coalesced ----
    __shared__ char tiles[65536];              // A: [0,32K), B: [32K,64K)
    {
        const char* srcA = (const char*)fbp + (size_t)bx * 32768;
#pragma unroll
        for (int q = 0; q < 8; q++)
            *(float4*)(tiles + q * 4096 + tid * 16) =
                *(const float4*)(srcA + q * 4096 + tid * 16);
        if (!diag) {
            const char* srcB = (const char*)fbp + (size_t)by * 32768;
#pragma unroll
            for (int q = 0; q < 8; q++)
                *(float4*)(tiles + 32768 + q * 4096 + tid * 16) =
                    *(const float4*)(srcB + q * 4096 + tid * 16);
        }
    }
    __syncthreads();
    const int boff = diag ? 0 : 32768;

    float pos = 0.f, neg = 0.f;

    if (!(diag && wx < wy)) {    // diag blocks: wx<wy waves cover only gi>gj
        // epilogue metadata loads first: latency hidden under MFMA loop
        float2 mj[4];
#pragma unroll
        for (int ni = 0; ni < 4; ni++) mj[ni] = meta[j0 + ni * 16 + l15];
        float2 mi[4][4];
#pragma unroll
        for (int m = 0; m < 4; m++)
#pragma unroll
            for (int r = 0; r < 4; r++) mi[m][r] = meta[i0 + m * 16 + quad * 4 + r];

        f32x4 acc4[4][4];
#pragma unroll
        for (int a = 0; a < 4; a++)
#pragma unroll
            for (int b = 0; b < 4; b++) acc4[a][b] = (f32x4){0.f, 0.f, 0.f, 0.f};

        // fragment ds_reads: lane*16B within a 1KB span -> conflict-free b128
        auto loadf = [&](int ks, bf16x8* af, bf16x8* bg) {
#pragma unroll
            for (int tt = 0; tt < 4; tt++)
                af[tt] = *(const bf16x8*)(tiles +
                    (((wy * 4 + tt) * 4 + ks) << 10) + lane * 16);
#pragma unroll
            for (int tt = 0; tt < 4; tt++)
                bg[tt] = *(const bf16x8*)(tiles + boff +
                    (((wx * 4 + tt) * 4 + ks) << 10) + lane * 16);
        };
        auto mfma16 = [&](bf16x8* af, bf16x8* bg) {
#pragma unroll
            for (int m = 0; m < 4; m++)
#pragma unroll
                for (int n = 0; n < 4; n++)
                    acc4[m][n] = __builtin_amdgcn_mfma_f32_16x16x32_bf16(
                        af[m], bg[n], acc4[m][n], 0, 0, 0);
        };

        // 2-deep software pipeline over the 4 k-steps (K=128)
        bf16x8 a0[4], b0[4], a1[4], b1[4];
        loadf(0, a0, b0);
        loadf(1, a1, b1);
        mfma16(a0, b0);
        loadf(2, a0, b0);
        mfma16(a1, b1);
        loadf(3, a1, b1);
        mfma16(a0, b0);
        mfma16(a1, b1);

        // epilogue. C/D: col = lane&15 (j), row = quad*4 + reg (i).
        const bool strict = diag && (wx == wy);  // same 64-subtile: need i<j
#pragma unroll
        for (int m = 0; m < 4; m++)
#pragma unroll
            for (int n = 0; n < 4; n++)
#pragma unroll
                for (int r = 0; r < 4; r++) {
                    int il = m * 16 + quad * 4 + r;
                    int jl = n * 16 + l15;
                    bool valid = !strict || (il < jl);
                    float d2 = fmaxf(mi[m][r].x + mj[n].x - 2.f * acc4[m][n][r], 0.f);
                    if (valid) {
                        if (mi[m][r].y == mj[n].y) pos += d2;
                        else if (d2 < 4.0f) {        // hinge active iff d < margin
                            float h = 2.0f - sqrtf(d2);
                            neg += h * h;
                        }
                    }
                }
    }

    // block reduction: wave shuffle, LDS across 4 waves, ONE plain store/block
#pragma unroll
    for (int off = 32; off > 0; off >>= 1) {
        pos += __shfl_down(pos, off, 64);
        neg += __shfl_down(neg, off, 64);
    }
    __shared__ float red[2][4];
    if (lane == 0) { red[0][wave] = pos; red[1][wave] = neg; }
    __syncthreads();
    if (tid == 0)
        partial[t] = make_float2(red[0][0] + red[0][1] + red[0][2] + red[0][3],
                                 red[1][0] + red[1][1] + red[1][2] + red[1][3]);
}

__global__ __launch_bounds__(256) void reduce_kernel(
        const float2* __restrict__ partial, float* __restrict__ out) {
    const int tid = threadIdx.x;
    float p = 0.f, n = 0.f;
    for (int i = tid; i < NBLOCKS; i += 256) {
        float2 v = partial[i];
        p += v.x; n += v.y;
    }
#pragma unroll
    for (int off = 32; off > 0; off >>= 1) {
        p += __shfl_down(p, off, 64);
        n += __shfl_down(n, off, 64);
    }
    __shared__ float red[2][4];
    int lane = tid & 63, w = tid >> 6;
    if (lane == 0) { red[0][w] = p; red[1][w] = n; }
    __syncthreads();
    if (tid == 0) {
        float total = 2.0f * (red[0][0] + red[0][1] + red[0][2] + red[0][3] +
                              red[1][0] + red[1][1] + red[1][2] + red[1][3]);
        out[0] = total / 67100672.0f;   // B*(B-1); pos pairs guaranteed (pigeonhole)
    }
}

extern "C" void kernel_launch(void* const* d_in, const int* in_sizes, int n_in,
                              void* d_out, int out_size, void* d_ws, size_t ws_size,
                              hipStream_t stream) {
    const float* f = (const float*)d_in[0];
    const int* labels = (const int*)d_in[1];
    float* out = (float*)d_out;

    // ws: fbp 2MB | meta 64KB | partial 16.6KB
    short* fbp = (short*)d_ws;
    float2* meta = (float2*)((char*)d_ws + (size_t)BN * DD * sizeof(short));
    float2* partial = meta + BN;

    prep_kernel<<<BN / 16, 256, 0, stream>>>(f, labels, fbp, meta);
    pair_kernel<<<NBLOCKS, 256, 0, stream>>>(fbp, meta, partial);
    reduce_kernel<<<1, 256, 0, stream>>>(partial, out);
}

// Round 8
// 87.631 us; speedup vs baseline: 1.0820x; 1.0820x over previous
//
#include <hip/hip_runtime.h>
#include <hip/hip_bf16.h>

// Contrastive loss, B=8192, D=128, 100 classes, margin=2.
// R8: OCCUPANCY. R4 counters: VALUBusy 8us + Mfma 3us vs 70us dur, occupancy
// 18.6% (~1.5 waves/SIMD) -- the kernel is stalled on cold cross-XCD L2/HBM
// fragment reads (~1000cyc) with too few waves to overlap them (Little's law
// needs ~25KB in flight/CU; one wave holds 8KB). Fix: force 4 waves/SIMD via
// __launch_bounds__(256,4): no reg double-buffer (R6 proved neutral: +VGPRs
// = -waves), meta loads moved AFTER the MFMA loop (peak regs ~115 < 128).
// Direct-from-L2 fragment loads (R7 proved LDS staging regresses: same cold
// misses, fewer resident blocks).
//   fbp[((p*4+ks)*64+lane)*8+j] = F_bf16[p*16+(lane&15)][ks*32+(lane>>4)*8+j]
// Known harness floor ~46us/iter (268MB d_ws 0xAA poison fill ~41us + restore).
// No global atomics (R4: same-address fp32 atomics serialize ~15ns each).
// pos_count>0 always: 8192 rows, 100 classes -> pigeonhole duplicate labels.

#define BN 8192
#define DD 128
#define NTILES 64                              // BN / 128
#define NBLOCKS (NTILES * (NTILES + 1) / 2)    // 2080
#define LS 136                                 // prep LDS row stride (shorts)

typedef __attribute__((ext_vector_type(8))) short bf16x8;   // 8 bf16 = 4 VGPRs
typedef __attribute__((ext_vector_type(4))) float f32x4;

// One block per 16-row panel. Coalesced read -> bf16 -> LDS transpose ->
// coalesced fragment-order write. Also emits (norm^2, label) meta.
__global__ __launch_bounds__(256) void prep_kernel(const float* __restrict__ f,
        const int* __restrict__ labels, short* __restrict__ fbp,
        float2* __restrict__ meta) {
    const int tid = threadIdx.x;
    const int p = blockIdx.x;                  // panel index (16 rows)
    __shared__ unsigned short ls[16][LS];

    const int r = tid >> 4;                    // row in panel (16 threads/row)
    const int c = (tid & 15) * 8;              // col of this thread's 8 floats
    const float* src = f + ((size_t)p * 16 + r) * DD + c;
    float4 a = *(const float4*)src;
    float4 b = *(const float4*)(src + 4);
    float rv[8] = {a.x, a.y, a.z, a.w, b.x, b.y, b.z, b.w};
    float s = 0.f;
#pragma unroll
    for (int j = 0; j < 8; j++) {
        __hip_bfloat16 h = __float2bfloat16(rv[j]);
        ls[r][c + j] = *(unsigned short*)&h;
        float rr = __bfloat162float(h);
        s = fmaf(rr, rr, s);
    }
    // row norm: reduce across the 16 consecutive lanes of this row
#pragma unroll
    for (int off = 8; off > 0; off >>= 1) s += __shfl_down(s, off, 16);
    if ((tid & 15) == 0) meta[p * 16 + r] = make_float2(s, (float)labels[p * 16 + r]);
    __syncthreads();

    // wave w = k-step ks; 16B/lane LDS read, 1KB contiguous global write
    const int w = tid >> 6, lane = tid & 63;
    const int l15 = lane & 15, quad = lane >> 4;
    bf16x8 pack = *(const bf16x8*)&ls[l15][w * 32 + quad * 8];
    *(bf16x8*)(fbp + ((size_t)(p * 4 + w) * 64 + lane) * 8) = pack;
}

__global__ __launch_bounds__(256, 4) void pair_kernel(
        const short* __restrict__ fbp, const float2* __restrict__ meta,
        float2* __restrict__ partial) {
    // triangular decode: block t -> (bx <= by); i-tile = bx, j-tile = by
    const int t = blockIdx.x;
    int by = (int)((sqrtf(8.f * (float)t + 1.f) - 1.f) * 0.5f);
    while ((by + 1) * (by + 2) / 2 <= t) by++;
    while (by * (by + 1) / 2 > t) by--;
    const int bx = t - by * (by + 1) / 2;
    const bool diag = (bx == by);

    const int tid = threadIdx.x;
    const int wave = tid >> 6, lane = tid & 63;
    const int wx = wave & 1, wy = wave >> 1;     // j / i subtile
    const int i0 = bx * 128 + wy * 64;
    const int j0 = by * 128 + wx * 64;
    const int ip = i0 >> 4, jp = j0 >> 4;        // panel indices
    const int l15 = lane & 15, quad = lane >> 4;

    float pos = 0.f, neg = 0.f;

    if (!(diag && wx < wy)) {    // diag blocks: wx<wy waves cover only gi>gj
        f32x4 acc4[4][4];
#pragma unroll
        for (int a = 0; a < 4; a++)
#pragma unroll
            for (int b = 0; b < 4; b++) acc4[a][b] = (f32x4){0.f, 0.f, 0.f, 0.f};

        // K = 128 = 4 k-steps; one fragment set live (peak regs low -> 4 w/SIMD)
#pragma unroll
        for (int ks = 0; ks < 4; ks++) {
            bf16x8 af[4], bg[4];
#pragma unroll
            for (int tt = 0; tt < 4; tt++)
                af[tt] = *(const bf16x8*)(fbp +
                    ((size_t)((ip + tt) * 4 + ks) * 64 + lane) * 8);
#pragma unroll
            for (int tt = 0; tt < 4; tt++)
                bg[tt] = *(const bf16x8*)(fbp +
                    ((size_t)((jp + tt) * 4 + ks) * 64 + lane) * 8);
#pragma unroll
            for (int m = 0; m < 4; m++)
#pragma unroll
                for (int n = 0; n < 4; n++)
                    acc4[m][n] = __builtin_amdgcn_mfma_f32_16x16x32_bf16(
                        af[m], bg[n], acc4[m][n], 0, 0, 0);
        }

        // epilogue metadata AFTER the MFMA loop: frag regs are dead here,
        // keeping peak VGPR below the 128 needed for 4 waves/SIMD.
        float2 mj[4];
#pragma unroll
        for (int ni = 0; ni < 4; ni++) mj[ni] = meta[j0 + ni * 16 + l15];
        float2 mi[4][4];
#pragma unroll
        for (int m = 0; m < 4; m++)
#pragma unroll
            for (int r = 0; r < 4; r++) mi[m][r] = meta[i0 + m * 16 + quad * 4 + r];

        // C/D: col = lane&15 (j), row = quad*4 + reg (i).
        const bool strict = diag && (wx == wy);  // same 64-subtile: need i<j
#pragma unroll
        for (int m = 0; m < 4; m++)
#pragma unroll
            for (int n = 0; n < 4; n++)
#pragma unroll
                for (int r = 0; r < 4; r++) {
                    int il = m * 16 + quad * 4 + r;
                    int jl = n * 16 + l15;
                    bool valid = !strict || (il < jl);
                    float d2 = fmaxf(mi[m][r].x + mj[n].x - 2.f * acc4[m][n][r], 0.f);
                    if (valid) {
                        if (mi[m][r].y == mj[n].y) pos += d2;
                        else if (d2 < 4.0f) {        // hinge active iff d < margin
                            float h = 2.0f - sqrtf(d2);
                            neg += h * h;
                        }
                    }
                }
    }

    // block reduction: wave shuffle, LDS across 4 waves, ONE plain store/block
#pragma unroll
    for (int off = 32; off > 0; off >>= 1) {
        pos += __shfl_down(pos, off, 64);
        neg += __shfl_down(neg, off, 64);
    }
    __shared__ float red[2][4];
    if (lane == 0) { red[0][wave] = pos; red[1][wave] = neg; }
    __syncthreads();
    if (tid == 0)
        partial[t] = make_float2(red[0][0] + red[0][1] + red[0][2] + red[0][3],
                                 red[1][0] + red[1][1] + red[1][2] + red[1][3]);
}

__global__ __launch_bounds__(256) void reduce_kernel(
        const float2* __restrict__ partial, float* __restrict__ out) {
    const int tid = threadIdx.x;
    float p = 0.f, n = 0.f;
    for (int i = tid; i < NBLOCKS; i += 256) {
        float2 v = partial[i];
        p += v.x; n += v.y;
    }
#pragma unroll
    for (int off = 32; off > 0; off >>= 1) {
        p += __shfl_down(p, off, 64);
        n += __shfl_down(n, off, 64);
    }
    __shared__ float red[2][4];
    int lane = tid & 63, w = tid >> 6;
    if (lane == 0) { red[0][w] = p; red[1][w] = n; }
    __syncthreads();
    if (tid == 0) {
        float total = 2.0f * (red[0][0] + red[0][1] + red[0][2] + red[0][3] +
                              red[1][0] + red[1][1] + red[1][2] + red[1][3]);
        out[0] = total / 67100672.0f;   // B*(B-1); pos pairs guaranteed (pigeonhole)
    }
}

extern "C" void kernel_launch(void* const* d_in, const int* in_sizes, int n_in,
                              void* d_out, int out_size, void* d_ws, size_t ws_size,
                              hipStream_t stream) {
    const float* f = (const float*)d_in[0];
    const int* labels = (const int*)d_in[1];
    float* out = (float*)d_out;

    // ws: fbp 2MB | meta 64KB | partial 16.6KB
    short* fbp = (short*)d_ws;
    float2* meta = (float2*)((char*)d_ws + (size_t)BN * DD * sizeof(short));
    float2* partial = meta + BN;

    prep_kernel<<<BN / 16, 256, 0, stream>>>(f, labels, fbp, meta);
    pair_kernel<<<NBLOCKS, 256, 0, stream>>>(fbp, meta, partial);
    reduce_kernel<<<1, 256, 0, stream>>>(partial, out);
}